// Round 1
// baseline (913.663 us; speedup 1.0000x reference)
//
#include <hip/hip_runtime.h>

// FlashQwenAttention: x@wq/wk/wv -> rmsnorm(q,k) -> rope -> GQA causal attn -> ctx@wo
// B=2 S=1024 H=4096 NH=32 NKV=8 HD=128. All inputs fp32; internal compute bf16 MFMA.

#define NH_ 32
#define NKV_ 8
#define HD_ 128
#define SEQ_ 1024
#define HID_ 4096
#define NQKV_ 6144

typedef unsigned short u16;
typedef __bf16 bf16x8 __attribute__((ext_vector_type(8)));
typedef float f32x4 __attribute__((ext_vector_type(4)));

__device__ __forceinline__ u16 f2bf(float f) {
  unsigned int u = __float_as_uint(f);
  return (u16)((u + 0x7FFFu + ((u >> 16) & 1u)) >> 16);
}
__device__ __forceinline__ float bf2f(u16 u) {
  return __uint_as_float(((unsigned int)u) << 16);
}
__device__ __forceinline__ f32x4 mfma16(bf16x8 a, bf16x8 b, f32x4 c) {
  return __builtin_amdgcn_mfma_f32_16x16x32_bf16(a, b, c, 0, 0, 0);
}

// ---------------- Kernel 1: fused QKV projection GEMM ----------------
// C[2048 x 6144] = X[2048 x 4096] @ [wq | wk | wv], output bf16.
__global__ __launch_bounds__(256) void qkv_gemm(
    const float* __restrict__ X, const float* __restrict__ WQ,
    const float* __restrict__ WK, const float* __restrict__ WV,
    u16* __restrict__ OUT) {
  __shared__ u16 As[128 * 40];  // A tile [m][k], pad 40
  __shared__ u16 Bs[128 * 40];  // B tile transposed [n][k], pad 40
  const int bn = blockIdx.x, bm = blockIdx.y;
  const int tid = threadIdx.x;
  const int lane = tid & 63, w = tid >> 6;
  const int wr = w >> 1, wc = w & 1;
  const int ln = lane & 15, quad = lane >> 4;

  const float* Wp;
  int ldw, c0 = bn * 128;
  if (c0 < 4096) { Wp = WQ; ldw = 4096; }
  else if (c0 < 5120) { Wp = WK; ldw = 1024; c0 -= 4096; }
  else { Wp = WV; ldw = 1024; c0 -= 5120; }

  const int arow = tid >> 1, ahalf = tid & 1;
  const int bk = tid >> 3, bseg = tid & 7;
  const float* asrc = X + (size_t)(bm * 128 + arow) * HID_ + ahalf * 16;
  const float* bsrc = Wp + (size_t)bk * ldw + c0 + bseg * 16;

  f32x4 acc[4][4];
#pragma unroll
  for (int i = 0; i < 4; ++i)
#pragma unroll
    for (int j = 0; j < 4; ++j)
#pragma unroll
      for (int r = 0; r < 4; ++r) acc[i][j][r] = 0.0f;

  for (int kb = 0; kb < HID_ / 32; ++kb) {
    {  // stage A (fp32 -> bf16)
      const float* s = asrc + kb * 32;
      u16 t16[16];
#pragma unroll
      for (int i = 0; i < 16; ++i) t16[i] = f2bf(s[i]);
      *(uint4*)&As[arow * 40 + ahalf * 16] = *(uint4*)&t16[0];
      *(uint4*)&As[arow * 40 + ahalf * 16 + 8] = *(uint4*)&t16[8];
    }
    {  // stage B transposed (fp32 -> bf16)
      const float* s = bsrc + (size_t)kb * 32 * ldw;
#pragma unroll
      for (int i = 0; i < 16; ++i) Bs[(bseg * 16 + i) * 40 + bk] = f2bf(s[i]);
    }
    __syncthreads();
    bf16x8 af[4], bfr[4];
#pragma unroll
    for (int i = 0; i < 4; ++i)
      af[i] = *(const bf16x8*)&As[(wr * 64 + i * 16 + ln) * 40 + quad * 8];
#pragma unroll
    for (int j = 0; j < 4; ++j)
      bfr[j] = *(const bf16x8*)&Bs[(wc * 64 + j * 16 + ln) * 40 + quad * 8];
#pragma unroll
    for (int i = 0; i < 4; ++i)
#pragma unroll
      for (int j = 0; j < 4; ++j) acc[i][j] = mfma16(af[i], bfr[j], acc[i][j]);
    __syncthreads();
  }
  // epilogue: C/D layout col=lane&15, row=quad*4+reg (m89-verified)
#pragma unroll
  for (int i = 0; i < 4; ++i) {
#pragma unroll
    for (int r = 0; r < 4; ++r) {
      int grow = bm * 128 + wr * 64 + i * 16 + quad * 4 + r;
      u16* dst = OUT + (size_t)grow * NQKV_ + bn * 128 + wc * 64 + ln;
#pragma unroll
      for (int j = 0; j < 4; ++j) dst[j * 16] = f2bf(acc[i][j][r]);
    }
  }
}

// ---------------- Kernel 2: RMSNorm + RoPE + layout transform ----------------
// one wave per 128-elem head vector; lane handles pair (l, l+64)
__global__ __launch_bounds__(256) void norm_rope(
    const u16* __restrict__ QKV, const float* __restrict__ QW,
    const float* __restrict__ KW, u16* __restrict__ QB, u16* __restrict__ KB,
    u16* __restrict__ VB) {
  int vec = blockIdx.x * 4 + (threadIdx.x >> 6);
  int lane = threadIdx.x & 63;
  const u16* src;
  u16* dst;
  const float* nw;
  int m;
  if (vec < 65536) {  // q: vec = m*32 + h
    m = vec >> 5;
    int hh = vec & 31;
    src = QKV + (size_t)m * NQKV_ + hh * 128;
    int b = m >> 10, s = m & 1023;
    dst = QB + (size_t)((b * NH_ + hh) * SEQ_ + s) * HD_;
    nw = QW;
  } else if (vec < 81920) {  // k
    int vk = vec - 65536;
    m = vk >> 3;
    int kvh = vk & 7;
    src = QKV + (size_t)m * NQKV_ + 4096 + kvh * 128;
    int b = m >> 10, s = m & 1023;
    dst = KB + (size_t)((b * NKV_ + kvh) * SEQ_ + s) * HD_;
    nw = KW;
  } else {  // v: convert + transpose only
    int vv = vec - 81920;
    m = vv >> 3;
    int kvh = vv & 7;
    src = QKV + (size_t)m * NQKV_ + 5120 + kvh * 128;
    int b = m >> 10, s = m & 1023;
    dst = VB + (size_t)((b * NKV_ + kvh) * SEQ_ + s) * HD_;
    dst[lane] = src[lane];
    dst[lane + 64] = src[lane + 64];
    return;
  }
  float t1 = bf2f(src[lane]), t2 = bf2f(src[lane + 64]);
  float ss = t1 * t1 + t2 * t2;
#pragma unroll
  for (int off = 32; off >= 1; off >>= 1) ss += __shfl_xor(ss, off);
  float scale = rsqrtf(ss * (1.0f / 128.0f) + 1e-6f);
  float n1 = t1 * scale * nw[lane];
  float n2 = t2 * scale * nw[lane + 64];
  int spos = m & 1023;
  float invf = powf(10000.0f, -(float)lane * (1.0f / 64.0f));
  float ang = (float)spos * invf;
  float sn, cs;
  sincosf(ang, &sn, &cs);
  dst[lane] = f2bf(n1 * cs - n2 * sn);
  dst[lane + 64] = f2bf(n1 * sn + n2 * cs);
}

// ---------------- Kernel 3: GQA causal flash attention ----------------
// block = (b, h, 64-row q tile); 4 waves x 16 q rows; 32-key tiles
__global__ __launch_bounds__(256) void flash_attn(
    const u16* __restrict__ QB, const u16* __restrict__ KB,
    const u16* __restrict__ VB, u16* __restrict__ CTX) {
  __shared__ u16 Ks[32 * 136];   // [key][d], pad 136
  __shared__ u16 Vt[128 * 40];   // [d][key], pad 40
  __shared__ u16 Pl[4][16 * 40]; // per-wave P in A-layout staging

  const int bid = blockIdx.x;
  const int qt = bid & 15, h = (bid >> 4) & 31, b = bid >> 9;
  const int kvh = h >> 2;
  const int tid = threadIdx.x;
  const int w = tid >> 6, lane = tid & 63;
  const int ln = lane & 15, quad = lane >> 4;

  // load Q fragments (held in registers whole kernel)
  const u16* qbase = QB + (size_t)((b * NH_ + h) * SEQ_ + qt * 64 + w * 16 + ln) * HD_;
  bf16x8 qf[4];
#pragma unroll
  for (int kc = 0; kc < 4; ++kc)
    qf[kc] = *(const bf16x8*)(qbase + kc * 32 + quad * 8);

  f32x4 o[8];
#pragma unroll
  for (int t = 0; t < 8; ++t)
#pragma unroll
    for (int r = 0; r < 4; ++r) o[t][r] = 0.0f;
  float m_r[4] = {-3e38f, -3e38f, -3e38f, -3e38f};
  float l_r[4] = {0.0f, 0.0f, 0.0f, 0.0f};

  const float sscale = 0.08838834764831845f;  // 1/sqrt(128)
  const int nkt = 2 * (qt + 1);
  const int skey = tid >> 3, dseg = (tid & 7) * 16;
  const u16* kbase = KB + (size_t)((b * NKV_ + kvh) * SEQ_) * HD_;
  const u16* vbase = VB + (size_t)((b * NKV_ + kvh) * SEQ_) * HD_;

  for (int kt = 0; kt < nkt; ++kt) {
    const int key0 = kt * 32;
    {  // stage K natural [key][d]
      const u16* s = kbase + (size_t)(key0 + skey) * HD_ + dseg;
      *(uint4*)&Ks[skey * 136 + dseg] = *(const uint4*)s;
      *(uint4*)&Ks[skey * 136 + dseg + 8] = *(const uint4*)(s + 8);
    }
    {  // stage V transposed [d][key]
      const u16* s = vbase + (size_t)(key0 + skey) * HD_ + dseg;
      u16 tmp[16];
      *(uint4*)&tmp[0] = *(const uint4*)s;
      *(uint4*)&tmp[8] = *(const uint4*)(s + 8);
#pragma unroll
      for (int i = 0; i < 16; ++i) Vt[(dseg + i) * 40 + skey] = tmp[i];
    }
    __syncthreads();

    // scores: S[16 x 32] = Q(16x128) @ K_tile^T
    f32x4 sc[2];
#pragma unroll
    for (int t2 = 0; t2 < 2; ++t2) {
#pragma unroll
      for (int r = 0; r < 4; ++r) sc[t2][r] = 0.0f;
#pragma unroll
      for (int kc = 0; kc < 4; ++kc) {
        bf16x8 bf = *(const bf16x8*)&Ks[(t2 * 16 + ln) * 136 + kc * 32 + quad * 8];
        sc[t2] = mfma16(qf[kc], bf, sc[t2]);
      }
    }

    // online softmax (rows = quad*4+r, keys = t2*16 + ln)
    float alpha_r[4], p0a[4], p1a[4];
#pragma unroll
    for (int r = 0; r < 4; ++r) {
      const int qi = qt * 64 + w * 16 + quad * 4 + r;
      float s0 = sc[0][r] * sscale;
      if (key0 + ln > qi) s0 = -3e38f;
      float s1 = sc[1][r] * sscale;
      if (key0 + 16 + ln > qi) s1 = -3e38f;
      float mx = fmaxf(s0, s1);
#pragma unroll
      for (int off = 1; off < 16; off <<= 1) mx = fmaxf(mx, __shfl_xor(mx, off));
      float mnew = fmaxf(m_r[r], mx);
      alpha_r[r] = __expf(m_r[r] - mnew);
      float p0 = __expf(s0 - mnew), p1 = __expf(s1 - mnew);
      float rs = p0 + p1;
#pragma unroll
      for (int off = 1; off < 16; off <<= 1) rs += __shfl_xor(rs, off);
      l_r[r] = l_r[r] * alpha_r[r] + rs;
      m_r[r] = mnew;
      p0a[r] = p0;
      p1a[r] = p1;
    }
#pragma unroll
    for (int t = 0; t < 8; ++t)
#pragma unroll
      for (int r = 0; r < 4; ++r) o[t][r] *= alpha_r[r];

    // P: C-layout -> A-layout via per-wave LDS (no cross-wave barrier needed)
#pragma unroll
    for (int r = 0; r < 4; ++r) {
      Pl[w][(quad * 4 + r) * 40 + ln] = f2bf(p0a[r]);
      Pl[w][(quad * 4 + r) * 40 + 16 + ln] = f2bf(p1a[r]);
    }
    bf16x8 af = *(const bf16x8*)&Pl[w][ln * 40 + quad * 8];
#pragma unroll
    for (int t = 0; t < 8; ++t) {
      bf16x8 vf = *(const bf16x8*)&Vt[(t * 16 + ln) * 40 + quad * 8];
      o[t] = mfma16(af, vf, o[t]);
    }
    __syncthreads();
  }

  // epilogue: O /= l, write ctx [b*S+s][h*128+d] bf16
#pragma unroll
  for (int r = 0; r < 4; ++r) {
    float inv_l = 1.0f / l_r[r];
    int srow = qt * 64 + w * 16 + quad * 4 + r;
    u16* dst = CTX + (size_t)(b * SEQ_ + srow) * (NH_ * HD_) + h * HD_;
#pragma unroll
    for (int t = 0; t < 8; ++t) dst[t * 16 + ln] = f2bf(o[t][r] * inv_l);
  }
}

// ---------------- Kernel 4: output projection GEMM ----------------
// OUT[2048 x 4096] fp32 = CTX[2048 x 4096] bf16 @ WO[4096 x 4096] fp32
__global__ __launch_bounds__(256) void out_gemm(
    const u16* __restrict__ CTX, const float* __restrict__ WO,
    float* __restrict__ OUT) {
  __shared__ u16 As[128 * 40];
  __shared__ u16 Bs[128 * 40];
  const int bn = blockIdx.x, bm = blockIdx.y;
  const int tid = threadIdx.x;
  const int lane = tid & 63, w = tid >> 6;
  const int wr = w >> 1, wc = w & 1;
  const int ln = lane & 15, quad = lane >> 4;

  const int arow = tid >> 1, ahalf = tid & 1;
  const int bk = tid >> 3, bseg = tid & 7;
  const u16* asrc = CTX + (size_t)(bm * 128 + arow) * HID_ + ahalf * 16;
  const float* bsrc = WO + (size_t)bk * HID_ + bn * 128 + bseg * 16;

  f32x4 acc[4][4];
#pragma unroll
  for (int i = 0; i < 4; ++i)
#pragma unroll
    for (int j = 0; j < 4; ++j)
#pragma unroll
      for (int r = 0; r < 4; ++r) acc[i][j][r] = 0.0f;

  for (int kb = 0; kb < HID_ / 32; ++kb) {
    {  // stage A (already bf16)
      const u16* s = asrc + kb * 32;
      *(uint4*)&As[arow * 40 + ahalf * 16] = *(const uint4*)s;
      *(uint4*)&As[arow * 40 + ahalf * 16 + 8] = *(const uint4*)(s + 8);
    }
    {  // stage B transposed (fp32 -> bf16)
      const float* s = bsrc + (size_t)kb * 32 * HID_;
#pragma unroll
      for (int i = 0; i < 16; ++i) Bs[(bseg * 16 + i) * 40 + bk] = f2bf(s[i]);
    }
    __syncthreads();
    bf16x8 af[4], bfr[4];
#pragma unroll
    for (int i = 0; i < 4; ++i)
      af[i] = *(const bf16x8*)&As[(wr * 64 + i * 16 + ln) * 40 + quad * 8];
#pragma unroll
    for (int j = 0; j < 4; ++j)
      bfr[j] = *(const bf16x8*)&Bs[(wc * 64 + j * 16 + ln) * 40 + quad * 8];
#pragma unroll
    for (int i = 0; i < 4; ++i)
#pragma unroll
      for (int j = 0; j < 4; ++j) acc[i][j] = mfma16(af[i], bfr[j], acc[i][j]);
    __syncthreads();
  }
#pragma unroll
  for (int i = 0; i < 4; ++i) {
#pragma unroll
    for (int r = 0; r < 4; ++r) {
      int grow = bm * 128 + wr * 64 + i * 16 + quad * 4 + r;
      float* dst = OUT + (size_t)grow * HID_ + bn * 128 + wc * 64 + ln;
#pragma unroll
      for (int j = 0; j < 4; ++j) dst[j * 16] = acc[i][j][r];
    }
  }
}

extern "C" void kernel_launch(void* const* d_in, const int* in_sizes, int n_in,
                              void* d_out, int out_size, void* d_ws,
                              size_t ws_size, hipStream_t stream) {
  const float* x = (const float*)d_in[0];
  const float* wq = (const float*)d_in[1];
  const float* wk = (const float*)d_in[2];
  const float* wv = (const float*)d_in[3];
  const float* wo = (const float*)d_in[4];
  const float* qw = (const float*)d_in[5];
  const float* kw = (const float*)d_in[6];
  float* out = (float*)d_out;
  char* ws = (char*)d_ws;

  // ws layout (bytes):
  //   [0, 24M):   qkv bf16 [2048][6144]   (dead after norm_rope; ctx reuses [0,16M))
  //   [24M, 40M): qb bf16 [2,32,1024,128]
  //   [40M, 44M): kb bf16 [2,8,1024,128]
  //   [44M, 48M): vb bf16 [2,8,1024,128]
  u16* qkv = (u16*)ws;
  u16* qb = (u16*)(ws + 25165824);
  u16* kb = (u16*)(ws + 25165824 + 16777216);
  u16* vb = (u16*)(ws + 25165824 + 16777216 + 4194304);
  u16* ctx = (u16*)ws;  // reuse qkv region

  qkv_gemm<<<dim3(48, 16), 256, 0, stream>>>(x, wq, wk, wv, qkv);
  norm_rope<<<dim3(24576), 256, 0, stream>>>(qkv, qw, kw, qb, kb, vb);
  flash_attn<<<dim3(1024), 256, 0, stream>>>(qb, kb, vb, ctx);
  out_gemm<<<dim3(32, 16), 256, 0, stream>>>(ctx, wo, out);
}

// Round 2
// 643.360 us; speedup vs baseline: 1.4201x; 1.4201x over previous
//
#include <hip/hip_runtime.h>

// FlashQwenAttention: x@wq/wk/wv -> rmsnorm(q,k) -> rope -> GQA causal attn -> ctx@wo
// B=2 S=1024 H=4096 NH=32 NKV=8 HD=128. Inputs fp32; internal bf16 MFMA.
// R2: m97-style GEMMs (global_load_lds width=16, B^T bf16, unpadded LDS) +
//     one-time weight transpose/convert prep kernels. Fallback to R1 path if
//     ws_size < 112 MB.

#define NH_ 32
#define NKV_ 8
#define HD_ 128
#define SEQ_ 1024
#define HID_ 4096
#define NQKV_ 6144

typedef unsigned short u16;
typedef __bf16 bf16x8 __attribute__((ext_vector_type(8)));
typedef float f32x4 __attribute__((ext_vector_type(4)));

__device__ __forceinline__ u16 f2bf(float f) {
  unsigned int u = __float_as_uint(f);
  return (u16)((u + 0x7FFFu + ((u >> 16) & 1u)) >> 16);
}
__device__ __forceinline__ float bf2f(u16 u) {
  return __uint_as_float(((unsigned int)u) << 16);
}
__device__ __forceinline__ f32x4 mfma16(bf16x8 a, bf16x8 b, f32x4 c) {
  return __builtin_amdgcn_mfma_f32_16x16x32_bf16(a, b, c, 0, 0, 0);
}
// async global->LDS, 16B per lane; lds base must be wave-uniform
__device__ __forceinline__ void gld16(u16* lds, const u16* g) {
  __builtin_amdgcn_global_load_lds(
      (const __attribute__((address_space(1))) unsigned int*)g,
      (__attribute__((address_space(3))) unsigned int*)lds, 16, 0, 0);
}

// ---------------- prep: fp32 -> bf16 elementwise (X) ----------------
__global__ __launch_bounds__(256) void cvt_bf16(const float* __restrict__ src,
                                                u16* __restrict__ dst) {
  int i = (blockIdx.x * 256 + threadIdx.x) * 8;
  float4 a = *(const float4*)(src + i);
  float4 b = *(const float4*)(src + i + 4);
  u16 o[8];
  o[0] = f2bf(a.x); o[1] = f2bf(a.y); o[2] = f2bf(a.z); o[3] = f2bf(a.w);
  o[4] = f2bf(b.x); o[5] = f2bf(b.y); o[6] = f2bf(b.z); o[7] = f2bf(b.w);
  *(uint4*)(dst + i) = *(uint4*)&o[0];
}

// ---------------- prep: transpose + convert weights ----------------
// src fp32 [K][ldn] tile(k0=bx*32, n0=by*32) -> dst bf16 [ldn-rows][K]
__global__ __launch_bounds__(256) void transpose_cvt(
    const float* __restrict__ src, int ldn, u16* __restrict__ dst, int K) {
  __shared__ float t[32][33];
  const int k0 = blockIdx.x * 32, n0 = blockIdx.y * 32;
  const int c = threadIdx.x & 31, r4 = threadIdx.x >> 5;  // r4 in 0..7
#pragma unroll
  for (int i = 0; i < 4; ++i) {
    int r = r4 + i * 8;
    t[r][c] = src[(size_t)(k0 + r) * ldn + n0 + c];
  }
  __syncthreads();
#pragma unroll
  for (int i = 0; i < 4; ++i) {
    int r = r4 + i * 8;
    dst[(size_t)(n0 + r) * K + k0 + c] = f2bf(t[c][r]);
  }
}

// ---------------- m97-style GEMM: C[M x N] = A[M x K] @ Bt[N x K]^T --------
// A,Bt bf16 row-major. 128x128 tile, BK=32, 4 waves (2x2 of 64x64).
template <bool F32OUT>
__global__ __launch_bounds__(256) void gemm_bt(const u16* __restrict__ A,
                                               const u16* __restrict__ Bt,
                                               void* __restrict__ Cv, int K,
                                               int ldc) {
  __shared__ u16 As[128 * 32];
  __shared__ u16 Bs[128 * 32];
  const int bn = blockIdx.x, bm = blockIdx.y;
  const int tid = threadIdx.x, lane = tid & 63, w = tid >> 6;
  const int wr = w >> 1, wc = w & 1, ln = lane & 15, quad = lane >> 4;

  // staging: inst j covers LDS rows w*32+j*16 .. +15; lane l -> row +l/4,
  // k-seg (l&3)*8 (LDS dst is uniform base + lane*16B)
  const int srow = w * 32 + (lane >> 2);
  const int skk = (lane & 3) * 8;
  const u16* ag = A + (size_t)(bm * 128 + srow) * K + skk;
  const u16* bg = Bt + (size_t)(bn * 128 + srow) * K + skk;
  u16* asd = &As[w * 1024];
  u16* bsd = &Bs[w * 1024];

  f32x4 acc[4][4];
#pragma unroll
  for (int i = 0; i < 4; ++i)
#pragma unroll
    for (int j = 0; j < 4; ++j)
#pragma unroll
      for (int r = 0; r < 4; ++r) acc[i][j][r] = 0.0f;

  for (int kb = 0; kb < K / 32; ++kb) {
    gld16(asd, ag);
    gld16(asd + 512, ag + 16 * (size_t)K);
    gld16(bsd, bg);
    gld16(bsd + 512, bg + 16 * (size_t)K);
    ag += 32;
    bg += 32;
    __syncthreads();
    bf16x8 af[4], bfr[4];
#pragma unroll
    for (int i = 0; i < 4; ++i)
      af[i] = *(const bf16x8*)&As[(wr * 64 + i * 16 + ln) * 32 + quad * 8];
#pragma unroll
    for (int j = 0; j < 4; ++j)
      bfr[j] = *(const bf16x8*)&Bs[(wc * 64 + j * 16 + ln) * 32 + quad * 8];
#pragma unroll
    for (int i = 0; i < 4; ++i)
#pragma unroll
      for (int j = 0; j < 4; ++j) acc[i][j] = mfma16(af[i], bfr[j], acc[i][j]);
    __syncthreads();
  }
  // C/D layout: col=lane&15, row=quad*4+reg
#pragma unroll
  for (int i = 0; i < 4; ++i) {
#pragma unroll
    for (int r = 0; r < 4; ++r) {
      int grow = bm * 128 + wr * 64 + i * 16 + quad * 4 + r;
      int gcol = bn * 128 + wc * 64 + ln;
      if (F32OUT) {
        float* dst = (float*)Cv + (size_t)grow * ldc + gcol;
#pragma unroll
        for (int j = 0; j < 4; ++j) dst[j * 16] = acc[i][j][r];
      } else {
        u16* dst = (u16*)Cv + (size_t)grow * ldc + gcol;
#pragma unroll
        for (int j = 0; j < 4; ++j) dst[j * 16] = f2bf(acc[i][j][r]);
      }
    }
  }
}

// ---------------- RMSNorm + RoPE + layout transform ----------------
__global__ __launch_bounds__(256) void norm_rope(
    const u16* __restrict__ QKV, const float* __restrict__ QW,
    const float* __restrict__ KW, u16* __restrict__ QB, u16* __restrict__ KB,
    u16* __restrict__ VB) {
  int vec = blockIdx.x * 4 + (threadIdx.x >> 6);
  int lane = threadIdx.x & 63;
  const u16* src;
  u16* dst;
  const float* nw;
  int m;
  if (vec < 65536) {  // q
    m = vec >> 5;
    int hh = vec & 31;
    src = QKV + (size_t)m * NQKV_ + hh * 128;
    int b = m >> 10, s = m & 1023;
    dst = QB + (size_t)((b * NH_ + hh) * SEQ_ + s) * HD_;
    nw = QW;
  } else if (vec < 81920) {  // k
    int vk = vec - 65536;
    m = vk >> 3;
    int kvh = vk & 7;
    src = QKV + (size_t)m * NQKV_ + 4096 + kvh * 128;
    int b = m >> 10, s = m & 1023;
    dst = KB + (size_t)((b * NKV_ + kvh) * SEQ_ + s) * HD_;
    nw = KW;
  } else {  // v: copy only
    int vv = vec - 81920;
    m = vv >> 3;
    int kvh = vv & 7;
    src = QKV + (size_t)m * NQKV_ + 5120 + kvh * 128;
    int b = m >> 10, s = m & 1023;
    dst = VB + (size_t)((b * NKV_ + kvh) * SEQ_ + s) * HD_;
    dst[lane] = src[lane];
    dst[lane + 64] = src[lane + 64];
    return;
  }
  float t1 = bf2f(src[lane]), t2 = bf2f(src[lane + 64]);
  float ss = t1 * t1 + t2 * t2;
#pragma unroll
  for (int off = 32; off >= 1; off >>= 1) ss += __shfl_xor(ss, off);
  float scale = rsqrtf(ss * (1.0f / 128.0f) + 1e-6f);
  float n1 = t1 * scale * nw[lane];
  float n2 = t2 * scale * nw[lane + 64];
  int spos = m & 1023;
  float invf = powf(10000.0f, -(float)lane * (1.0f / 64.0f));
  float ang = (float)spos * invf;
  float sn, cs;
  sincosf(ang, &sn, &cs);
  dst[lane] = f2bf(n1 * cs - n2 * sn);
  dst[lane + 64] = f2bf(n1 * sn + n2 * cs);
}

// ---------------- GQA causal flash attention ----------------
__global__ __launch_bounds__(256) void flash_attn(
    const u16* __restrict__ QB, const u16* __restrict__ KB,
    const u16* __restrict__ VB, u16* __restrict__ CTX) {
  __shared__ u16 Ks[32 * 136];
  __shared__ u16 Vt[128 * 40];
  __shared__ u16 Pl[4][16 * 40];

  const int bid = blockIdx.x;
  const int qt = bid & 15, h = (bid >> 4) & 31, b = bid >> 9;
  const int kvh = h >> 2;
  const int tid = threadIdx.x;
  const int w = tid >> 6, lane = tid & 63;
  const int ln = lane & 15, quad = lane >> 4;

  const u16* qbase =
      QB + (size_t)((b * NH_ + h) * SEQ_ + qt * 64 + w * 16 + ln) * HD_;
  bf16x8 qf[4];
#pragma unroll
  for (int kc = 0; kc < 4; ++kc)
    qf[kc] = *(const bf16x8*)(qbase + kc * 32 + quad * 8);

  f32x4 o[8];
#pragma unroll
  for (int t = 0; t < 8; ++t)
#pragma unroll
    for (int r = 0; r < 4; ++r) o[t][r] = 0.0f;
  float m_r[4] = {-3e38f, -3e38f, -3e38f, -3e38f};
  float l_r[4] = {0.0f, 0.0f, 0.0f, 0.0f};

  const float sscale = 0.08838834764831845f;
  const int nkt = 2 * (qt + 1);
  const int skey = tid >> 3, dseg = (tid & 7) * 16;
  const u16* kbase = KB + (size_t)((b * NKV_ + kvh) * SEQ_) * HD_;
  const u16* vbase = VB + (size_t)((b * NKV_ + kvh) * SEQ_) * HD_;

  for (int kt = 0; kt < nkt; ++kt) {
    const int key0 = kt * 32;
    {
      const u16* s = kbase + (size_t)(key0 + skey) * HD_ + dseg;
      *(uint4*)&Ks[skey * 136 + dseg] = *(const uint4*)s;
      *(uint4*)&Ks[skey * 136 + dseg + 8] = *(const uint4*)(s + 8);
    }
    {
      const u16* s = vbase + (size_t)(key0 + skey) * HD_ + dseg;
      u16 tmp[16];
      *(uint4*)&tmp[0] = *(const uint4*)s;
      *(uint4*)&tmp[8] = *(const uint4*)(s + 8);
#pragma unroll
      for (int i = 0; i < 16; ++i) Vt[(dseg + i) * 40 + skey] = tmp[i];
    }
    __syncthreads();

    f32x4 sc[2];
#pragma unroll
    for (int t2 = 0; t2 < 2; ++t2) {
#pragma unroll
      for (int r = 0; r < 4; ++r) sc[t2][r] = 0.0f;
#pragma unroll
      for (int kc = 0; kc < 4; ++kc) {
        bf16x8 bf = *(const bf16x8*)&Ks[(t2 * 16 + ln) * 136 + kc * 32 + quad * 8];
        sc[t2] = mfma16(qf[kc], bf, sc[t2]);
      }
    }

    float alpha_r[4], p0a[4], p1a[4];
#pragma unroll
    for (int r = 0; r < 4; ++r) {
      const int qi = qt * 64 + w * 16 + quad * 4 + r;
      float s0 = sc[0][r] * sscale;
      if (key0 + ln > qi) s0 = -3e38f;
      float s1 = sc[1][r] * sscale;
      if (key0 + 16 + ln > qi) s1 = -3e38f;
      float mx = fmaxf(s0, s1);
#pragma unroll
      for (int off = 1; off < 16; off <<= 1) mx = fmaxf(mx, __shfl_xor(mx, off));
      float mnew = fmaxf(m_r[r], mx);
      alpha_r[r] = __expf(m_r[r] - mnew);
      float p0 = __expf(s0 - mnew), p1 = __expf(s1 - mnew);
      float rs = p0 + p1;
#pragma unroll
      for (int off = 1; off < 16; off <<= 1) rs += __shfl_xor(rs, off);
      l_r[r] = l_r[r] * alpha_r[r] + rs;
      m_r[r] = mnew;
      p0a[r] = p0;
      p1a[r] = p1;
    }
#pragma unroll
    for (int t = 0; t < 8; ++t)
#pragma unroll
      for (int r = 0; r < 4; ++r) o[t][r] *= alpha_r[r];

#pragma unroll
    for (int r = 0; r < 4; ++r) {
      Pl[w][(quad * 4 + r) * 40 + ln] = f2bf(p0a[r]);
      Pl[w][(quad * 4 + r) * 40 + 16 + ln] = f2bf(p1a[r]);
    }
    bf16x8 af = *(const bf16x8*)&Pl[w][ln * 40 + quad * 8];
#pragma unroll
    for (int t = 0; t < 8; ++t) {
      bf16x8 vf = *(const bf16x8*)&Vt[(t * 16 + ln) * 40 + quad * 8];
      o[t] = mfma16(af, vf, o[t]);
    }
    __syncthreads();
  }

#pragma unroll
  for (int r = 0; r < 4; ++r) {
    float inv_l = 1.0f / l_r[r];
    int srow = qt * 64 + w * 16 + quad * 4 + r;
    u16* dst = CTX + (size_t)(b * SEQ_ + srow) * (NH_ * HD_) + h * HD_;
#pragma unroll
    for (int t = 0; t < 8; ++t) dst[t * 16 + ln] = f2bf(o[t][r] * inv_l);
  }
}

// ================= fallback (R1) GEMMs, used if ws too small =================
__global__ __launch_bounds__(256) void qkv_gemm_f32w(
    const float* __restrict__ X, const float* __restrict__ WQ,
    const float* __restrict__ WK, const float* __restrict__ WV,
    u16* __restrict__ OUT) {
  __shared__ u16 As[128 * 40];
  __shared__ u16 Bs[128 * 40];
  const int bn = blockIdx.x, bm = blockIdx.y;
  const int tid = threadIdx.x;
  const int lane = tid & 63, w = tid >> 6;
  const int wr = w >> 1, wc = w & 1;
  const int ln = lane & 15, quad = lane >> 4;
  const float* Wp;
  int ldw, c0 = bn * 128;
  if (c0 < 4096) { Wp = WQ; ldw = 4096; }
  else if (c0 < 5120) { Wp = WK; ldw = 1024; c0 -= 4096; }
  else { Wp = WV; ldw = 1024; c0 -= 5120; }
  const int arow = tid >> 1, ahalf = tid & 1;
  const int bk = tid >> 3, bseg = tid & 7;
  const float* asrc = X + (size_t)(bm * 128 + arow) * HID_ + ahalf * 16;
  const float* bsrc = Wp + (size_t)bk * ldw + c0 + bseg * 16;
  f32x4 acc[4][4];
#pragma unroll
  for (int i = 0; i < 4; ++i)
#pragma unroll
    for (int j = 0; j < 4; ++j)
#pragma unroll
      for (int r = 0; r < 4; ++r) acc[i][j][r] = 0.0f;
  for (int kb = 0; kb < HID_ / 32; ++kb) {
    {
      const float* s = asrc + kb * 32;
      u16 t16[16];
#pragma unroll
      for (int i = 0; i < 16; ++i) t16[i] = f2bf(s[i]);
      *(uint4*)&As[arow * 40 + ahalf * 16] = *(uint4*)&t16[0];
      *(uint4*)&As[arow * 40 + ahalf * 16 + 8] = *(uint4*)&t16[8];
    }
    {
      const float* s = bsrc + (size_t)kb * 32 * ldw;
#pragma unroll
      for (int i = 0; i < 16; ++i) Bs[(bseg * 16 + i) * 40 + bk] = f2bf(s[i]);
    }
    __syncthreads();
    bf16x8 af[4], bfr[4];
#pragma unroll
    for (int i = 0; i < 4; ++i)
      af[i] = *(const bf16x8*)&As[(wr * 64 + i * 16 + ln) * 40 + quad * 8];
#pragma unroll
    for (int j = 0; j < 4; ++j)
      bfr[j] = *(const bf16x8*)&Bs[(wc * 64 + j * 16 + ln) * 40 + quad * 8];
#pragma unroll
    for (int i = 0; i < 4; ++i)
#pragma unroll
      for (int j = 0; j < 4; ++j) acc[i][j] = mfma16(af[i], bfr[j], acc[i][j]);
    __syncthreads();
  }
#pragma unroll
  for (int i = 0; i < 4; ++i) {
#pragma unroll
    for (int r = 0; r < 4; ++r) {
      int grow = bm * 128 + wr * 64 + i * 16 + quad * 4 + r;
      u16* dst = OUT + (size_t)grow * NQKV_ + bn * 128 + wc * 64 + ln;
#pragma unroll
      for (int j = 0; j < 4; ++j) dst[j * 16] = f2bf(acc[i][j][r]);
    }
  }
}

__global__ __launch_bounds__(256) void out_gemm_f32w(
    const u16* __restrict__ CTX, const float* __restrict__ WO,
    float* __restrict__ OUT) {
  __shared__ u16 As[128 * 40];
  __shared__ u16 Bs[128 * 40];
  const int bn = blockIdx.x, bm = blockIdx.y;
  const int tid = threadIdx.x;
  const int lane = tid & 63, w = tid >> 6;
  const int wr = w >> 1, wc = w & 1;
  const int ln = lane & 15, quad = lane >> 4;
  const int arow = tid >> 1, ahalf = tid & 1;
  const int bk = tid >> 3, bseg = tid & 7;
  const u16* asrc = CTX + (size_t)(bm * 128 + arow) * HID_ + ahalf * 16;
  const float* bsrc = WO + (size_t)bk * HID_ + bn * 128 + bseg * 16;
  f32x4 acc[4][4];
#pragma unroll
  for (int i = 0; i < 4; ++i)
#pragma unroll
    for (int j = 0; j < 4; ++j)
#pragma unroll
      for (int r = 0; r < 4; ++r) acc[i][j][r] = 0.0f;
  for (int kb = 0; kb < HID_ / 32; ++kb) {
    {
      const u16* s = asrc + kb * 32;
      *(uint4*)&As[arow * 40 + ahalf * 16] = *(const uint4*)s;
      *(uint4*)&As[arow * 40 + ahalf * 16 + 8] = *(const uint4*)(s + 8);
    }
    {
      const float* s = bsrc + (size_t)kb * 32 * HID_;
#pragma unroll
      for (int i = 0; i < 16; ++i) Bs[(bseg * 16 + i) * 40 + bk] = f2bf(s[i]);
    }
    __syncthreads();
    bf16x8 af[4], bfr[4];
#pragma unroll
    for (int i = 0; i < 4; ++i)
      af[i] = *(const bf16x8*)&As[(wr * 64 + i * 16 + ln) * 40 + quad * 8];
#pragma unroll
    for (int j = 0; j < 4; ++j)
      bfr[j] = *(const bf16x8*)&Bs[(wc * 64 + j * 16 + ln) * 40 + quad * 8];
#pragma unroll
    for (int i = 0; i < 4; ++i)
#pragma unroll
      for (int j = 0; j < 4; ++j) acc[i][j] = mfma16(af[i], bfr[j], acc[i][j]);
    __syncthreads();
  }
#pragma unroll
  for (int i = 0; i < 4; ++i) {
#pragma unroll
    for (int r = 0; r < 4; ++r) {
      int grow = bm * 128 + wr * 64 + i * 16 + quad * 4 + r;
      float* dst = OUT + (size_t)grow * HID_ + bn * 128 + wc * 64 + ln;
#pragma unroll
      for (int j = 0; j < 4; ++j) dst[j * 16] = acc[i][j][r];
    }
  }
}

extern "C" void kernel_launch(void* const* d_in, const int* in_sizes, int n_in,
                              void* d_out, int out_size, void* d_ws,
                              size_t ws_size, hipStream_t stream) {
  const float* x = (const float*)d_in[0];
  const float* wq = (const float*)d_in[1];
  const float* wk = (const float*)d_in[2];
  const float* wv = (const float*)d_in[3];
  const float* wo = (const float*)d_in[4];
  const float* qw = (const float*)d_in[5];
  const float* kw = (const float*)d_in[6];
  float* out = (float*)d_out;
  char* ws = (char*)d_ws;
  const size_t MB = 1024 * 1024;

  if (ws_size >= 112 * MB) {
    // fast path layout:
    //  [0,48M):  WQKVT bf16 [6144][4096]  -> after qkv_gemm: WOT bf16 [4096][4096] at [0,32M)
    //  [48,64M): Xb bf16 [2048][4096]     (dead after qkv_gemm)
    //  [64,88M): qkv bf16 [2048][6144]    -> after norm_rope: ctx bf16 at [64,80M)
    //  [88,104M): qb  [104,108M): kb  [108,112M): vb
    u16* wqkvt = (u16*)ws;
    u16* wot = (u16*)ws;
    u16* xb = (u16*)(ws + 48 * MB);
    u16* qkv = (u16*)(ws + 64 * MB);
    u16* ctx = (u16*)(ws + 64 * MB);
    u16* qb = (u16*)(ws + 88 * MB);
    u16* kb = (u16*)(ws + 104 * MB);
    u16* vb = (u16*)(ws + 108 * MB);

    cvt_bf16<<<dim3(4096), 256, 0, stream>>>(x, xb);
    transpose_cvt<<<dim3(128, 128), 256, 0, stream>>>(wq, 4096, wqkvt, 4096);
    transpose_cvt<<<dim3(128, 32), 256, 0, stream>>>(
        wk, 1024, wqkvt + (size_t)4096 * 4096, 4096);
    transpose_cvt<<<dim3(128, 32), 256, 0, stream>>>(
        wv, 1024, wqkvt + (size_t)5120 * 4096, 4096);
    gemm_bt<false><<<dim3(48, 16), 256, 0, stream>>>(xb, wqkvt, qkv, 4096, 6144);
    transpose_cvt<<<dim3(128, 128), 256, 0, stream>>>(wo, 4096, wot, 4096);
    norm_rope<<<dim3(24576), 256, 0, stream>>>(qkv, qw, kw, qb, kb, vb);
    flash_attn<<<dim3(1024), 256, 0, stream>>>(qb, kb, vb, ctx);
    gemm_bt<true><<<dim3(32, 16), 256, 0, stream>>>(ctx, wot, out, 4096, 4096);
  } else {
    // fallback (R1) layout, 48 MB
    u16* qkv = (u16*)ws;
    u16* qb = (u16*)(ws + 25165824);
    u16* kb = (u16*)(ws + 25165824 + 16777216);
    u16* vb = (u16*)(ws + 25165824 + 16777216 + 4194304);
    u16* ctx = (u16*)ws;
    qkv_gemm_f32w<<<dim3(48, 16), 256, 0, stream>>>(x, wq, wk, wv, qkv);
    norm_rope<<<dim3(24576), 256, 0, stream>>>(qkv, qw, kw, qb, kb, vb);
    flash_attn<<<dim3(1024), 256, 0, stream>>>(qb, kb, vb, ctx);
    out_gemm_f32w<<<dim3(32, 16), 256, 0, stream>>>(ctx, wo, out);
  }
}

// Round 3
// 542.799 us; speedup vs baseline: 1.6832x; 1.1853x over previous
//
#include <hip/hip_runtime.h>

// FlashQwenAttention: x@wq/wk/wv -> rmsnorm(q,k) -> rope -> GQA causal attn -> ctx@wo
// B=2 S=1024 H=4096 NH=32 NKV=8 HD=128. Inputs fp32; internal bf16 MFMA.
// R3: flash_attn rewrite — 64-key tiles, global_load_lds staging for K and
// pre-transposed V, swizzled P buffer, diagonal-only masking, qt-descending
// dispatch, Q prescaled by softmax_scale*log2e in norm_rope.

#define NH_ 32
#define NKV_ 8
#define HD_ 128
#define SEQ_ 1024
#define HID_ 4096
#define NQKV_ 6144

typedef unsigned short u16;
typedef __bf16 bf16x8 __attribute__((ext_vector_type(8)));
typedef float f32x4 __attribute__((ext_vector_type(4)));

__device__ __forceinline__ u16 f2bf(float f) {
  unsigned int u = __float_as_uint(f);
  return (u16)((u + 0x7FFFu + ((u >> 16) & 1u)) >> 16);
}
__device__ __forceinline__ float bf2f(u16 u) {
  return __uint_as_float(((unsigned int)u) << 16);
}
__device__ __forceinline__ f32x4 mfma16(bf16x8 a, bf16x8 b, f32x4 c) {
  return __builtin_amdgcn_mfma_f32_16x16x32_bf16(a, b, c, 0, 0, 0);
}
__device__ __forceinline__ void gld16(u16* lds, const u16* g) {
  __builtin_amdgcn_global_load_lds(
      (const __attribute__((address_space(1))) unsigned int*)g,
      (__attribute__((address_space(3))) unsigned int*)lds, 16, 0, 0);
}

// ---------------- prep: fp32 -> bf16 elementwise (X) ----------------
__global__ __launch_bounds__(256) void cvt_bf16(const float* __restrict__ src,
                                                u16* __restrict__ dst) {
  int i = (blockIdx.x * 256 + threadIdx.x) * 8;
  float4 a = *(const float4*)(src + i);
  float4 b = *(const float4*)(src + i + 4);
  u16 o[8];
  o[0] = f2bf(a.x); o[1] = f2bf(a.y); o[2] = f2bf(a.z); o[3] = f2bf(a.w);
  o[4] = f2bf(b.x); o[5] = f2bf(b.y); o[6] = f2bf(b.z); o[7] = f2bf(b.w);
  *(uint4*)(dst + i) = *(uint4*)&o[0];
}

// ---------------- prep: transpose + convert weights ----------------
__global__ __launch_bounds__(256) void transpose_cvt(
    const float* __restrict__ src, int ldn, u16* __restrict__ dst, int K) {
  __shared__ float t[32][33];
  const int k0 = blockIdx.x * 32, n0 = blockIdx.y * 32;
  const int c = threadIdx.x & 31, r4 = threadIdx.x >> 5;
#pragma unroll
  for (int i = 0; i < 4; ++i) {
    int r = r4 + i * 8;
    t[r][c] = src[(size_t)(k0 + r) * ldn + n0 + c];
  }
  __syncthreads();
#pragma unroll
  for (int i = 0; i < 4; ++i) {
    int r = r4 + i * 8;
    dst[(size_t)(n0 + r) * K + k0 + c] = f2bf(t[c][r]);
  }
}

// ---------------- prep: V section of qkv -> VT [b][kvh][d][s] bf16 -------
__global__ __launch_bounds__(256) void v_transpose(const u16* __restrict__ QKV,
                                                   u16* __restrict__ VT) {
  __shared__ u16 t[32][33];
  const int s0 = blockIdx.x * 32, d0 = blockIdx.y * 32;
  const int bkvh = blockIdx.z;
  const int b = bkvh >> 3, kvh = bkvh & 7;
  const int c = threadIdx.x & 31, r8 = threadIdx.x >> 5;
#pragma unroll
  for (int i = 0; i < 4; ++i) {
    int r = r8 + i * 8;
    t[r][c] = QKV[(size_t)(b * SEQ_ + s0 + r) * NQKV_ + 5120 + kvh * 128 + d0 + c];
  }
  __syncthreads();
#pragma unroll
  for (int i = 0; i < 4; ++i) {
    int r = r8 + i * 8;
    VT[(size_t)(bkvh * HD_ + d0 + r) * SEQ_ + s0 + c] = t[c][r];
  }
}

// ---------------- m97-style GEMM: C[M x N] = A[M x K] @ Bt[N x K]^T --------
template <bool F32OUT>
__global__ __launch_bounds__(256) void gemm_bt(const u16* __restrict__ A,
                                               const u16* __restrict__ Bt,
                                               void* __restrict__ Cv, int K,
                                               int ldc) {
  __shared__ u16 As[128 * 32];
  __shared__ u16 Bs[128 * 32];
  const int bn = blockIdx.x, bm = blockIdx.y;
  const int tid = threadIdx.x, lane = tid & 63, w = tid >> 6;
  const int wr = w >> 1, wc = w & 1, ln = lane & 15, quad = lane >> 4;

  const int srow = w * 32 + (lane >> 2);
  const int skk = (lane & 3) * 8;
  const u16* ag = A + (size_t)(bm * 128 + srow) * K + skk;
  const u16* bg = Bt + (size_t)(bn * 128 + srow) * K + skk;
  u16* asd = &As[w * 1024];
  u16* bsd = &Bs[w * 1024];

  f32x4 acc[4][4];
#pragma unroll
  for (int i = 0; i < 4; ++i)
#pragma unroll
    for (int j = 0; j < 4; ++j)
#pragma unroll
      for (int r = 0; r < 4; ++r) acc[i][j][r] = 0.0f;

  for (int kb = 0; kb < K / 32; ++kb) {
    gld16(asd, ag);
    gld16(asd + 512, ag + 16 * (size_t)K);
    gld16(bsd, bg);
    gld16(bsd + 512, bg + 16 * (size_t)K);
    ag += 32;
    bg += 32;
    __syncthreads();
    bf16x8 af[4], bfr[4];
#pragma unroll
    for (int i = 0; i < 4; ++i)
      af[i] = *(const bf16x8*)&As[(wr * 64 + i * 16 + ln) * 32 + quad * 8];
#pragma unroll
    for (int j = 0; j < 4; ++j)
      bfr[j] = *(const bf16x8*)&Bs[(wc * 64 + j * 16 + ln) * 32 + quad * 8];
#pragma unroll
    for (int i = 0; i < 4; ++i)
#pragma unroll
      for (int j = 0; j < 4; ++j) acc[i][j] = mfma16(af[i], bfr[j], acc[i][j]);
    __syncthreads();
  }
#pragma unroll
  for (int i = 0; i < 4; ++i) {
#pragma unroll
    for (int r = 0; r < 4; ++r) {
      int grow = bm * 128 + wr * 64 + i * 16 + quad * 4 + r;
      int gcol = bn * 128 + wc * 64 + ln;
      if (F32OUT) {
        float* dst = (float*)Cv + (size_t)grow * ldc + gcol;
#pragma unroll
        for (int j = 0; j < 4; ++j) dst[j * 16] = acc[i][j][r];
      } else {
        u16* dst = (u16*)Cv + (size_t)grow * ldc + gcol;
#pragma unroll
        for (int j = 0; j < 4; ++j) dst[j * 16] = f2bf(acc[i][j][r]);
      }
    }
  }
}

// ---------------- RMSNorm + RoPE (q prescaled by scale*log2e) -------------
__global__ __launch_bounds__(256) void norm_rope(
    const u16* __restrict__ QKV, const float* __restrict__ QW,
    const float* __restrict__ KW, u16* __restrict__ QB, u16* __restrict__ KB) {
  const float QSCALE = 0.08838834764831845f * 1.4426950408889634f;
  int vec = blockIdx.x * 4 + (threadIdx.x >> 6);
  int lane = threadIdx.x & 63;
  const u16* src;
  u16* dst;
  const float* nw;
  int m;
  float outsc;
  if (vec < 65536) {  // q
    m = vec >> 5;
    int hh = vec & 31;
    src = QKV + (size_t)m * NQKV_ + hh * 128;
    int b = m >> 10, s = m & 1023;
    dst = QB + (size_t)((b * NH_ + hh) * SEQ_ + s) * HD_;
    nw = QW;
    outsc = QSCALE;
  } else {  // k
    int vk = vec - 65536;
    m = vk >> 3;
    int kvh = vk & 7;
    src = QKV + (size_t)m * NQKV_ + 4096 + kvh * 128;
    int b = m >> 10, s = m & 1023;
    dst = KB + (size_t)((b * NKV_ + kvh) * SEQ_ + s) * HD_;
    nw = KW;
    outsc = 1.0f;
  }
  float t1 = bf2f(src[lane]), t2 = bf2f(src[lane + 64]);
  float ss = t1 * t1 + t2 * t2;
#pragma unroll
  for (int off = 32; off >= 1; off >>= 1) ss += __shfl_xor(ss, off);
  float scale = rsqrtf(ss * (1.0f / 128.0f) + 1e-6f) * outsc;
  float n1 = t1 * scale * nw[lane];
  float n2 = t2 * scale * nw[lane + 64];
  int spos = m & 1023;
  float invf = powf(10000.0f, -(float)lane * (1.0f / 64.0f));
  float ang = (float)spos * invf;
  float sn, cs;
  sincosf(ang, &sn, &cs);
  dst[lane] = f2bf(n1 * cs - n2 * sn);
  dst[lane + 64] = f2bf(n1 * sn + n2 * cs);
}

// ---------------- GQA causal flash attention (64-key tiles) ----------------
// block = (b, h, 64-row q tile); 4 waves x 16 q rows; qt-descending order
__global__ __launch_bounds__(256) void flash_attn(
    const u16* __restrict__ QB, const u16* __restrict__ KB,
    const u16* __restrict__ VT, u16* __restrict__ CTX) {
  __shared__ u16 Ks[4][64][32];   // [kc][key][k-seg]   16 KB
  __shared__ u16 Vs[2][128][32];  // [kchunk][d][key]   16 KB
  __shared__ u16 Pl[4][16][72];   // per-wave P, A-layout, XOR-bit3 swizzle

  const int bid = blockIdx.x;
  const int qt = 15 - (bid >> 6);           // long blocks dispatch first
  const int h = bid & 31, b = (bid >> 5) & 1;
  const int kvh = h >> 2;
  const int tid = threadIdx.x, w = tid >> 6, lane = tid & 63;
  const int ln = lane & 15, quad = lane >> 4;
  const int l4 = lane >> 2, l4r = lane & 3;

  const u16* qbase =
      QB + (size_t)((b * NH_ + h) * SEQ_ + qt * 64 + w * 16 + ln) * HD_;
  bf16x8 qf[4];
#pragma unroll
  for (int kc = 0; kc < 4; ++kc)
    qf[kc] = *(const bf16x8*)(qbase + kc * 32 + quad * 8);

  f32x4 o[8];
#pragma unroll
  for (int t = 0; t < 8; ++t)
#pragma unroll
    for (int r = 0; r < 4; ++r) o[t][r] = 0.0f;
  float m_r[4] = {-3e38f, -3e38f, -3e38f, -3e38f};
  float l_r[4] = {0.0f, 0.0f, 0.0f, 0.0f};

  const u16* krow = KB + (size_t)((b * NKV_ + kvh) * SEQ_ + w * 16 + l4) * HD_ +
                    l4r * 8;
  const u16* vrow = VT + (size_t)((b * NKV_ + kvh) * HD_ + w * 32 + l4) * SEQ_ +
                    l4r * 8;
  const int pswz = ((ln >> 3) & 1) << 3;  // read-side swizzle (row = ln)

  for (int kt = 0; kt <= qt; ++kt) {
    const int key0 = kt * 64;
    // stage K [key][128] -> Ks[kc][key][32] via DMA
#pragma unroll
    for (int i = 0; i < 4; ++i)
      gld16(&Ks[i][w * 16][0], krow + (size_t)key0 * HD_ + i * 32);
    // stage V^T [d][S] -> Vs[kchunk][d][32] via DMA
#pragma unroll
    for (int i = 0; i < 4; ++i)
      gld16(&Vs[i & 1][w * 32 + (i >> 1) * 16][0],
            vrow + (size_t)(i >> 1) * 16 * SEQ_ + key0 + (i & 1) * 32);
    __syncthreads();

    // scores: 4 tiles of 16 keys
    f32x4 sc[4];
#pragma unroll
    for (int t2 = 0; t2 < 4; ++t2) {
#pragma unroll
      for (int r = 0; r < 4; ++r) sc[t2][r] = 0.0f;
#pragma unroll
      for (int kc = 0; kc < 4; ++kc) {
        bf16x8 kf = *(const bf16x8*)&Ks[kc][t2 * 16 + ln][quad * 8];
        sc[t2] = mfma16(qf[kc], kf, sc[t2]);
      }
    }

    const bool diag = (kt == qt);
    float p[4][4], alpha[4];
#pragma unroll
    for (int r = 0; r < 4; ++r) {
      float s0 = sc[0][r], s1 = sc[1][r], s2 = sc[2][r], s3 = sc[3][r];
      if (diag) {
        const int qi = qt * 64 + w * 16 + quad * 4 + r;
        if (key0 + ln > qi) s0 = -3e38f;
        if (key0 + 16 + ln > qi) s1 = -3e38f;
        if (key0 + 32 + ln > qi) s2 = -3e38f;
        if (key0 + 48 + ln > qi) s3 = -3e38f;
      }
      float mx = fmaxf(fmaxf(s0, s1), fmaxf(s2, s3));
#pragma unroll
      for (int off = 1; off < 16; off <<= 1) mx = fmaxf(mx, __shfl_xor(mx, off));
      float mnew = fmaxf(m_r[r], mx);
      alpha[r] = exp2f(m_r[r] - mnew);
      p[0][r] = exp2f(s0 - mnew);
      p[1][r] = exp2f(s1 - mnew);
      p[2][r] = exp2f(s2 - mnew);
      p[3][r] = exp2f(s3 - mnew);
      float rs = p[0][r] + p[1][r] + p[2][r] + p[3][r];
#pragma unroll
      for (int off = 1; off < 16; off <<= 1) rs += __shfl_xor(rs, off);
      l_r[r] = l_r[r] * alpha[r] + rs;
      m_r[r] = mnew;
    }
#pragma unroll
    for (int t = 0; t < 8; ++t)
#pragma unroll
      for (int r = 0; r < 4; ++r) o[t][r] *= alpha[r];

    // P: C-layout -> A-layout via per-wave LDS, XOR-bit3 bank swizzle
#pragma unroll
    for (int r = 0; r < 4; ++r) {
      const int row = quad * 4 + r;
      const int wswz = ((row >> 3) & 1) << 3;
#pragma unroll
      for (int t2 = 0; t2 < 4; ++t2)
        Pl[w][row][(t2 * 16 + ln) ^ wswz] = f2bf(p[t2][r]);
    }
    bf16x8 af0 = *(const bf16x8*)&Pl[w][ln][(quad * 8) ^ pswz];
    bf16x8 af1 = *(const bf16x8*)&Pl[w][ln][32 + ((quad * 8) ^ pswz)];
#pragma unroll
    for (int t = 0; t < 8; ++t) {
      bf16x8 vf0 = *(const bf16x8*)&Vs[0][t * 16 + ln][quad * 8];
      o[t] = mfma16(af0, vf0, o[t]);
      bf16x8 vf1 = *(const bf16x8*)&Vs[1][t * 16 + ln][quad * 8];
      o[t] = mfma16(af1, vf1, o[t]);
    }
    __syncthreads();
  }

#pragma unroll
  for (int r = 0; r < 4; ++r) {
    float inv_l = 1.0f / l_r[r];
    int srow = qt * 64 + w * 16 + quad * 4 + r;
    u16* dst = CTX + (size_t)(b * SEQ_ + srow) * (NH_ * HD_) + h * HD_;
#pragma unroll
    for (int t = 0; t < 8; ++t) dst[t * 16 + ln] = f2bf(o[t][r] * inv_l);
  }
}

extern "C" void kernel_launch(void* const* d_in, const int* in_sizes, int n_in,
                              void* d_out, int out_size, void* d_ws,
                              size_t ws_size, hipStream_t stream) {
  const float* x = (const float*)d_in[0];
  const float* wq = (const float*)d_in[1];
  const float* wk = (const float*)d_in[2];
  const float* wv = (const float*)d_in[3];
  const float* wo = (const float*)d_in[4];
  const float* qw = (const float*)d_in[5];
  const float* kw = (const float*)d_in[6];
  float* out = (float*)d_out;
  char* ws = (char*)d_ws;
  const size_t MB = 1024 * 1024;

  //  [0,48M):  WQKVT bf16 [6144][4096]  -> after qkv_gemm: WOT bf16 at [0,32M)
  //  [48,64M): Xb bf16 [2048][4096]     (dead after qkv_gemm)
  //  [64,88M): qkv bf16 [2048][6144]    -> after attn inputs built: ctx at [64,80M)
  //  [88,104M): qb  [104,108M): kb  [108,112M): VT [16][128][1024]
  u16* wqkvt = (u16*)ws;
  u16* wot = (u16*)ws;
  u16* xb = (u16*)(ws + 48 * MB);
  u16* qkv = (u16*)(ws + 64 * MB);
  u16* ctx = (u16*)(ws + 64 * MB);
  u16* qb = (u16*)(ws + 88 * MB);
  u16* kb = (u16*)(ws + 104 * MB);
  u16* vt = (u16*)(ws + 108 * MB);

  cvt_bf16<<<dim3(4096), 256, 0, stream>>>(x, xb);
  transpose_cvt<<<dim3(128, 128), 256, 0, stream>>>(wq, 4096, wqkvt, 4096);
  transpose_cvt<<<dim3(128, 32), 256, 0, stream>>>(
      wk, 1024, wqkvt + (size_t)4096 * 4096, 4096);
  transpose_cvt<<<dim3(128, 32), 256, 0, stream>>>(
      wv, 1024, wqkvt + (size_t)5120 * 4096, 4096);
  gemm_bt<false><<<dim3(48, 16), 256, 0, stream>>>(xb, wqkvt, qkv, 4096, 6144);
  transpose_cvt<<<dim3(128, 128), 256, 0, stream>>>(wo, 4096, wot, 4096);
  norm_rope<<<dim3(20480), 256, 0, stream>>>(qkv, qw, kw, qb, kb);
  v_transpose<<<dim3(32, 4, 16), 256, 0, stream>>>(qkv, vt);
  flash_attn<<<dim3(1024), 256, 0, stream>>>(qb, kb, vt, ctx);
  gemm_bt<true><<<dim3(32, 16), 256, 0, stream>>>(ctx, wot, out, 4096, 4096);
}